// Round 1
// baseline (283.854 us; speedup 1.0000x reference)
//
#include <hip/hip_runtime.h>
#include <stdint.h>

// Problem constants
#define E_DIM 256
#define HEADS 8
#define NQ 49
#define S_TOT 196      // 14*14
#define S_PAD 208      // 13*16
#define NROIS 512
#define FH 152
#define FW 256
#define HW_TOT (FH*FW) // 38912

// LDS strides (u16 units). Chosen so row-per-lane b64 frag reads are bank-perfect:
// dword strides 134 (cf), 114 (attn/vT), 22 (kh/ore) all give 16 distinct banks.
#define CF_ST 268
#define AT_ST 228
#define KH_ST 44
#define VT_ST 228
#define OR_ST 44
#define AS_ST 260

typedef unsigned short u16;
typedef short bf16x8 __attribute__((ext_vector_type(8)));
typedef float f32x4 __attribute__((ext_vector_type(4)));

#define MFMA(a,b,c) __builtin_amdgcn_mfma_f32_16x16x32_bf16((a),(b),(c),0,0,0)

__device__ __forceinline__ u16 f2bf(float f) {
  union { float f; uint32_t u; } v; v.f = f;
  uint32_t u = v.u;
  return (u16)((u + 0x7FFFu + ((u >> 16) & 1u)) >> 16);
}
__device__ __forceinline__ float bf2f(u16 h) {
  union { uint32_t u; float f; } v; v.u = ((uint32_t)h) << 16;
  return v.f;
}
// LDS fragment load as two ds_read_b64 (8B-aligned rows)
__device__ __forceinline__ bf16x8 ld_frag(const u16* p) {
  union { uint2 d[2]; bf16x8 v; } t;
  t.d[0] = *(const uint2*)(p);
  t.d[1] = *(const uint2*)(p + 4);
  return t.v;
}
// Global 16B fragment load
__device__ __forceinline__ bf16x8 ld_frag_g(const u16* p) {
  union { uint4 d; bf16x8 v; } t;
  t.d = *(const uint4*)(p);
  return t.v;
}

struct SMem {
  u16 cf[S_PAD][CF_ST];            // 111,488 B  (bf16 cf tile, rows 196..207 zero)
  union {
    struct {
      u16 vT[32][VT_ST];           // 14,592 B   (v transposed: [d][s], cols 208..223 zero)
      union {
        u16 kh[S_PAD][KH_ST];      // 18,304 B   (k normal: [s][d])
        u16 attn[64][AT_ST];       // 29,184 B   (attn bf16: [q][s], cols 208..223 zero)
        u16 ore[64][OR_ST];        //  5,632 B   (per-head o redistribution)
      } a;
    } b;
    u16 ast[64][AS_ST];            // 33,280 B   (final att staging, phase C only)
  } r;
};                                  // total 155,264 B

// ---------------- pre-kernels ----------------

// features [256][HW] f32 -> fmapT [HW][256] bf16 (coalesced both sides via LDS tile)
__global__ void transpose_fmap(const float* __restrict__ f, u16* __restrict__ fT) {
  __shared__ float tile[64][65];
  int hw0 = blockIdx.x * 64;
  int t = threadIdx.x;
  int tr = t >> 6, tc = t & 63;
  for (int cc = 0; cc < 4; ++cc) {
#pragma unroll
    for (int i = 0; i < 16; ++i) {
      int cl = tr + 4*i;
      tile[cl][tc] = f[(cc*64 + cl)*HW_TOT + hw0 + tc];
    }
    __syncthreads();
#pragma unroll
    for (int i = 0; i < 16; ++i) {
      int hwl = tr + 4*i;
      fT[(size_t)(hw0 + hwl)*256 + cc*64 + tc] = f2bf(tile[tc][hwl]);
    }
    __syncthreads();
  }
}

// Wk, Wv (rows 256..767 of in_proj_weight), Wout -> bf16
__global__ void conv_weights(const float* __restrict__ ipw, const float* __restrict__ opw,
                             u16* __restrict__ Wk, u16* __restrict__ Wv, u16* __restrict__ Wo) {
  int i = blockIdx.x*256 + threadIdx.x;
  if (i < 65536) {
    Wk[i] = f2bf(ipw[65536 + i]);
    Wv[i] = f2bf(ipw[131072 + i]);
    Wo[i] = f2bf(opw[i]);
  }
}

// qs[h][64][32] bf16 = (cq @ Wq_h^T + bq_h) / sqrt(32), rows 49..63 zero
__global__ void compute_qs(const float* __restrict__ cq, const float* __restrict__ ipw,
                           const float* __restrict__ ipb, u16* __restrict__ qs) {
  int h = blockIdx.x;
  int t = threadIdx.x;
  for (int r = 0; r < 8; ++r) {
    int o = t + 256*r;            // 0..2047
    int qq = o >> 5, d = o & 31;
    float acc = 0.f;
    if (qq < NQ) {
      acc = ipb[h*32 + d];
      const float4* wr = (const float4*)(ipw + (size_t)(h*32 + d)*256);
      const float4* cr = (const float4*)(cq + (size_t)qq*256);
      float s = 0.f;
      for (int e = 0; e < 64; ++e) {
        float4 a = cr[e], b = wr[e];
        s += a.x*b.x + a.y*b.y + a.z*b.z + a.w*b.w;
      }
      acc = (acc + s) * 0.17677669529663687f;   // 1/sqrt(32)
    }
    qs[h*2048 + o] = f2bf(acc);
  }
}

// ---------------- main fused kernel: one ROI per block ----------------
__global__ __launch_bounds__(256, 1) void fused_roi_attn(
    const float* __restrict__ rois,
    const float* __restrict__ balance_p,
    const float* __restrict__ bv,       // in_proj_bias + 512
    const float* __restrict__ bout,
    const u16*  __restrict__ fmapT,     // [HW][256] bf16
    const u16*  __restrict__ Wkbf,      // [256][256]
    const u16*  __restrict__ Wvbf,
    const u16*  __restrict__ Woutbf,
    const u16*  __restrict__ qsPad,     // [8][64][32]
    float* __restrict__ out)            // [512][256][49]
{
  __shared__ SMem sm;
  const int tid = threadIdx.x;
  const int lane = tid & 63;
  const int w = tid >> 6;        // wave 0..3
  const int g = lane >> 4;       // quarter group 0..3
  const int l15 = lane & 15;
  const int n = blockIdx.x;

  // ---- Phase A: RoIAlign sampling -> cf bf16 in LDS ----
  float x1 = rois[n*5 + 1], y1 = rois[n*5 + 2], x2 = rois[n*5 + 3], y2 = rois[n*5 + 4];
  const float sc = 1.0f/16.0f;
  float sx = x1*sc - 0.5f, sy = y1*sc - 0.5f;
  float bw = (x2 - x1)*sc * (1.0f/14.0f);
  float bh = (y2 - y1)*sc * (1.0f/14.0f);
#pragma unroll 4
  for (int ii = 0; ii < 49; ++ii) {
    int s = w*49 + ii;
    int gy = s / 14, gx = s - gy*14;
    float y = sy + ((float)gy + 0.5f)*bh;
    float x = sx + ((float)gx + 0.5f)*bw;
    float valid = (y >= -1.0f && y <= (float)FH && x >= -1.0f && x <= (float)FW) ? 1.0f : 0.0f;
    float yc = fminf(fmaxf(y, 0.0f), (float)(FH-1));
    float xc = fminf(fmaxf(x, 0.0f), (float)(FW-1));
    float y0f = floorf(yc), x0f = floorf(xc);
    int y0 = (int)y0f, x0 = (int)x0f;
    int y1i = min(y0+1, FH-1), x1i = min(x0+1, FW-1);
    float ly = yc - y0f, lx = xc - x0f;
    float hy = 1.0f - ly, hx = 1.0f - lx;
    float w00 = hy*hx*valid, w01 = hy*lx*valid, w10 = ly*hx*valid, w11 = ly*lx*valid;
    int i00 = (y0*FW  + x0 )*E_DIM + 4*lane;
    int i01 = (y0*FW  + x1i)*E_DIM + 4*lane;
    int i10 = (y1i*FW + x0 )*E_DIM + 4*lane;
    int i11 = (y1i*FW + x1i)*E_DIM + 4*lane;
    ushort4 t00 = *(const ushort4*)(fmapT + i00);
    ushort4 t01 = *(const ushort4*)(fmapT + i01);
    ushort4 t10 = *(const ushort4*)(fmapT + i10);
    ushort4 t11 = *(const ushort4*)(fmapT + i11);
    ushort4 o;
    o.x = f2bf(w00*bf2f(t00.x) + w01*bf2f(t01.x) + w10*bf2f(t10.x) + w11*bf2f(t11.x));
    o.y = f2bf(w00*bf2f(t00.y) + w01*bf2f(t01.y) + w10*bf2f(t10.y) + w11*bf2f(t11.y));
    o.z = f2bf(w00*bf2f(t00.z) + w01*bf2f(t01.z) + w10*bf2f(t10.z) + w11*bf2f(t11.z));
    o.w = f2bf(w00*bf2f(t00.w) + w01*bf2f(t01.w) + w10*bf2f(t10.w) + w11*bf2f(t11.w));
    *(ushort4*)(&sm.cf[s][4*lane]) = o;
  }
  // zero cf pad rows 196..207
  for (int idx = tid; idx < (S_PAD - S_TOT)*CF_ST; idx += 256) {
    sm.cf[S_TOT + idx/CF_ST][idx % CF_ST] = 0;
  }
  // zero vT K-pad cols 208..223
  for (int idx = tid; idx < 32*16; idx += 256) {
    sm.r.b.vT[idx >> 4][208 + (idx & 15)] = 0;
  }

  float bal;
  { float bp = balance_p[0]; bal = fminf(fmaxf(bp*(1.0f/6.0f) + 0.5f, 0.0f), 1.0f); }

  // persistent out-projection accumulators: att[q=16w+4g+i][eo=16nt+l15]
  f32x4 attacc[16];
#pragma unroll
  for (int i = 0; i < 16; ++i) attacc[i] = (f32x4){0.f,0.f,0.f,0.f};

  for (int h = 0; h < HEADS; ++h) {
    __syncthreads();   // cf/vT ready (h=0); prior-head ore reads done (h>0)

    // ---- B1: k_h = cf@Wk_h^T (pass0), vT_h = (cf@Wv_h^T)^T (pass1) ----
#pragma unroll
    for (int pass = 0; pass < 2; ++pass) {
      const u16* Wb = pass ? Wvbf : Wkbf;
      bf16x8 bW[8][2];
#pragma unroll
      for (int kt = 0; kt < 8; ++kt)
#pragma unroll
        for (int nt = 0; nt < 2; ++nt)
          bW[kt][nt] = ld_frag_g(Wb + (size_t)(h*32 + nt*16 + l15)*256 + kt*32 + 8*g);
      for (int mt = w; mt < 13; mt += 4) {
        bf16x8 a[8];
#pragma unroll
        for (int kt = 0; kt < 8; ++kt)
          a[kt] = ld_frag(&sm.cf[mt*16 + l15][kt*32 + 8*g]);
        f32x4 acc0 = (f32x4){0.f,0.f,0.f,0.f}, acc1 = (f32x4){0.f,0.f,0.f,0.f};
#pragma unroll
        for (int kt = 0; kt < 8; ++kt) {
          acc0 = MFMA(a[kt], bW[kt][0], acc0);
          acc1 = MFMA(a[kt], bW[kt][1], acc1);
        }
        if (pass == 0) {
#pragma unroll
          for (int i = 0; i < 4; ++i) {
            int s = mt*16 + 4*g + i;
            sm.r.b.a.kh[s][l15]      = f2bf(acc0[i]);
            sm.r.b.a.kh[s][16 + l15] = f2bf(acc1[i]);
          }
        } else {
          ushort4 p0, p1;
          p0.x = f2bf(acc0[0]); p0.y = f2bf(acc0[1]); p0.z = f2bf(acc0[2]); p0.w = f2bf(acc0[3]);
          p1.x = f2bf(acc1[0]); p1.y = f2bf(acc1[1]); p1.z = f2bf(acc1[2]); p1.w = f2bf(acc1[3]);
          *(ushort4*)(&sm.r.b.vT[l15][mt*16 + 4*g])      = p0;
          *(ushort4*)(&sm.r.b.vT[16 + l15][mt*16 + 4*g]) = p1;
        }
      }
    }
    __syncthreads();   // k,v visible to all waves

    // ---- B2: logits[q=16w+4g+i][s=16nt+l15], K=32 (one MFMA per n-tile) ----
    bf16x8 aq = ld_frag_g(qsPad + (size_t)(h*64 + 16*w + l15)*32 + 8*g);
    f32x4 lac[13];
#pragma unroll
    for (int nt = 0; nt < 13; ++nt) {
      bf16x8 bk = ld_frag(&sm.r.b.a.kh[nt*16 + l15][8*g]);
      f32x4 z = (f32x4){0.f,0.f,0.f,0.f};
      lac[nt] = MFMA(aq, bk, z);
    }
    if (l15 >= 4) {    // mask s >= 196 (n-tile 12)
#pragma unroll
      for (int i = 0; i < 4; ++i) lac[12][i] = -1e30f;
    }
    // ---- B3: softmax over s (13 regs x 16 lanes of the N-group) ----
    float srow[4];
#pragma unroll
    for (int i = 0; i < 4; ++i) {
      float m = lac[0][i];
#pragma unroll
      for (int nt = 1; nt < 13; ++nt) m = fmaxf(m, lac[nt][i]);
#pragma unroll
      for (int off = 1; off < 16; off <<= 1) m = fmaxf(m, __shfl_xor(m, off, 64));
      float sumv = 0.f;
#pragma unroll
      for (int nt = 0; nt < 13; ++nt) {
        float p = __expf(lac[nt][i] - m);
        lac[nt][i] = p; sumv += p;
      }
#pragma unroll
      for (int off = 1; off < 16; off <<= 1) sumv += __shfl_xor(sumv, off, 64);
      srow[i] = 1.0f / sumv;
    }
    __syncthreads();   // all waves done reading kh before attn overwrites it
#pragma unroll
    for (int nt = 0; nt < 13; ++nt)
#pragma unroll
      for (int i = 0; i < 4; ++i)
        sm.r.b.a.attn[16*w + 4*g + i][nt*16 + l15] = f2bf(lac[nt][i] * srow[i]);
#pragma unroll
    for (int i = 0; i < 4; ++i)     // zero K-pad cols 208..223
      sm.r.b.a.attn[16*w + 4*g + i][208 + l15] = 0;

    // ---- B4: o_h = attn @ v (wave-local attn rows; vT cross-wave but post-barrier) ----
    f32x4 oacc0 = (f32x4){0.f,0.f,0.f,0.f}, oacc1 = (f32x4){0.f,0.f,0.f,0.f};
#pragma unroll
    for (int kt = 0; kt < 7; ++kt) {
      bf16x8 ap = ld_frag(&sm.r.b.a.attn[16*w + l15][kt*32 + 8*g]);
      bf16x8 b0 = ld_frag(&sm.r.b.vT[l15][kt*32 + 8*g]);
      bf16x8 b1 = ld_frag(&sm.r.b.vT[16 + l15][kt*32 + 8*g]);
      oacc0 = MFMA(ap, b0, oacc0);
      oacc1 = MFMA(ap, b1, oacc1);
    }
    __syncthreads();   // all waves done reading attn before ore overwrites region

    // bias (bv commutes: sum(attn)=1) + redistribute o to A-fragment layout
    float bv0 = bv[h*32 + l15];
    float bv1 = bv[h*32 + 16 + l15];
#pragma unroll
    for (int i = 0; i < 4; ++i) {
      sm.r.b.a.ore[16*w + 4*g + i][l15]      = f2bf(oacc0[i] + bv0);
      sm.r.b.a.ore[16*w + 4*g + i][16 + l15] = f2bf(oacc1[i] + bv1);
    }
    // ---- out-projection K-split accumulate (wave-local ore rows) ----
    bf16x8 ao = ld_frag(&sm.r.b.a.ore[16*w + l15][8*g]);
#pragma unroll
    for (int nt = 0; nt < 16; ++nt) {
      bf16x8 bo = ld_frag_g(Woutbf + (size_t)(nt*16 + l15)*256 + h*32 + 8*g);
      attacc[nt] = MFMA(ao, bo, attacc[nt]);
    }
  } // heads

  // ---- Phase C: stage att, fuse pos = 2x2 avgpool(cf), coalesced store ----
  __syncthreads();   // last ore reads done before ast overwrites region
#pragma unroll
  for (int nt = 0; nt < 16; ++nt) {
    float bo = bout[nt*16 + l15];
#pragma unroll
    for (int i = 0; i < 4; ++i)
      sm.r.ast[16*w + 4*g + i][nt*16 + l15] = f2bf(attacc[nt][i] + bo);
  }
  __syncthreads();
  float ibal = 1.0f - bal;
  float* outp = out + (size_t)n * (E_DIM * NQ);
  for (int j = 0; j < 49; ++j) {
    int idx = j*256 + tid;          // 12544 = 49*256 exactly
    int eo = idx / 49;
    int q  = idx - eo*49;
    int oy = q / 7, ox = q - oy*7;
    int r0 = (2*oy)*14 + 2*ox;
    float pos = 0.25f*(bf2f(sm.cf[r0][eo])    + bf2f(sm.cf[r0+1][eo]) +
                       bf2f(sm.cf[r0+14][eo]) + bf2f(sm.cf[r0+15][eo]));
    float att = bf2f(sm.r.ast[q][eo]);
    outp[idx] = bal*pos + ibal*att;
  }
}

// ---------------- launcher ----------------
// ws layout: fmapT bf16 19,922,944 | Wk 131,072 | Wv 131,072 | Wo 131,072 | qs 32,768
// total 20,348,928 B
extern "C" void kernel_launch(void* const* d_in, const int* in_sizes, int n_in,
                              void* d_out, int out_size, void* d_ws, size_t ws_size,
                              hipStream_t stream) {
  const float* features = (const float*)d_in[0];
  const float* rois     = (const float*)d_in[1];
  const float* cq       = (const float*)d_in[2];
  const float* ipw      = (const float*)d_in[3];
  const float* ipb      = (const float*)d_in[4];
  const float* opw      = (const float*)d_in[5];
  const float* opb      = (const float*)d_in[6];
  const float* balp     = (const float*)d_in[7];
  float* out = (float*)d_out;

  char* ws = (char*)d_ws;
  u16* fmapT = (u16*)ws;
  u16* Wk = (u16*)(ws + 19922944);
  u16* Wv = Wk + 65536;
  u16* Wo = Wv + 65536;
  u16* qs = Wo + 65536;

  hipLaunchKernelGGL(transpose_fmap, dim3(608), dim3(256), 0, stream, features, fmapT);
  hipLaunchKernelGGL(conv_weights,   dim3(256), dim3(256), 0, stream, ipw, opw, Wk, Wv, Wo);
  hipLaunchKernelGGL(compute_qs,     dim3(8),   dim3(256), 0, stream, cq, ipw, ipb, qs);
  hipLaunchKernelGGL(fused_roi_attn, dim3(NROIS), dim3(256), 0, stream,
                     rois, balp, ipb + 512, opb, fmapT, Wk, Wv, Wo, qs, out);
}

// Round 2
// 234.850 us; speedup vs baseline: 1.2087x; 1.2087x over previous
//
#include <hip/hip_runtime.h>
#include <stdint.h>

// Problem constants
#define E_DIM 256
#define HEADS 8
#define NQ 49
#define S_TOT 196      // 14*14
#define NROIS 512
#define FH 152
#define FW 256
#define HW_TOT (FH*FW) // 38912

// LDS strides (u16 units), chosen bank-friendly + 8B-aligned rows
#define KH_ST 44
#define VT_ST 228
#define AT_ST 228
#define OR_ST 44
#define AS_ST 260
#define PS_ST 260

typedef unsigned short u16;
typedef short bf16x8 __attribute__((ext_vector_type(8)));
typedef float f32x4 __attribute__((ext_vector_type(4)));
typedef unsigned short us8 __attribute__((ext_vector_type(8)));

#define MFMA(a,b,c) __builtin_amdgcn_mfma_f32_16x16x32_bf16((a),(b),(c),0,0,0)

__device__ __forceinline__ u16 f2bf(float f) {
  union { float f; uint32_t u; } v; v.f = f;
  uint32_t u = v.u;
  return (u16)((u + 0x7FFFu + ((u >> 16) & 1u)) >> 16);
}
__device__ __forceinline__ float bf2f(u16 h) {
  union { uint32_t u; float f; } v; v.u = ((uint32_t)h) << 16;
  return v.f;
}
__device__ __forceinline__ bf16x8 ld_frag(const u16* p) {   // 2x ds_read_b64
  union { uint2 d[2]; bf16x8 v; } t;
  t.d[0] = *(const uint2*)(p);
  t.d[1] = *(const uint2*)(p + 4);
  return t.v;
}
__device__ __forceinline__ bf16x8 ld_frag_g(const u16* p) { // 16B global
  union { uint4 d; bf16x8 v; } t;
  t.d = *(const uint4*)(p);
  return t.v;
}
__device__ __forceinline__ ushort4 pack4(float a, float b, float c, float d) {
  ushort4 r; r.x = f2bf(a); r.y = f2bf(b); r.z = f2bf(c); r.w = f2bf(d); return r;
}

// ---------------- K0: weights -> bf16 ----------------
__global__ void conv_weights(const float* __restrict__ ipw, const float* __restrict__ opw,
                             u16* __restrict__ Wk, u16* __restrict__ Wv, u16* __restrict__ Wo) {
  int i = blockIdx.x*256 + threadIdx.x;
  if (i < 65536) {
    Wk[i] = f2bf(ipw[65536 + i]);
    Wv[i] = f2bf(ipw[131072 + i]);
    Wo[i] = f2bf(opw[i]);
  }
}

// ---------------- K1: fmapT (bf16 transpose) + fmapK/fmapV = fmap^T @ W^T ----------------
// Projection commutes with bilinear sampling: k[s] = sum_p w_p * fmapK[p].
__global__ __launch_bounds__(256, 2) void prep_fmaps(
    const float* __restrict__ f, const u16* __restrict__ Wk, const u16* __restrict__ Wv,
    u16* __restrict__ fT, u16* __restrict__ fK, u16* __restrict__ fV)
{
  __shared__ u16 At[64][268];        // 34,304 B  (m x c bf16 tile)
  const int m0 = blockIdx.x << 6;
  const int t = threadIdx.x;
  const int lane = t & 63;
  const int w = t >> 6;
  const int g = lane >> 4;
  const int l15 = lane & 15;

  // stage + convert: features [256][HW] f32 -> At [64 m][256 c] bf16
#pragma unroll
  for (int i = 0; i < 16; ++i) {
    int c = (i << 4) + (t >> 4);
    int mm = (t & 15) << 2;
    float4 v = *(const float4*)(f + (size_t)c*HW_TOT + m0 + mm);
    At[mm][c] = f2bf(v.x); At[mm+1][c] = f2bf(v.y);
    At[mm+2][c] = f2bf(v.z); At[mm+3][c] = f2bf(v.w);
  }
  __syncthreads();

  // fT write (coalesced rows)
  {
    int r = t >> 2, cb = (t & 3) << 6;
    u16* dst = fT + (size_t)(m0 + r)*256 + cb;
#pragma unroll
    for (int i = 0; i < 16; ++i)
      *(ushort4*)(dst + (i << 2)) = *(const ushort4*)(&At[r][cb + (i << 2)]);
  }

  // GEMM: waves 0,1 -> K; waves 2,3 -> V; each wave: 32 m-rows x 256 n
  const u16* W = (w < 2) ? Wk : Wv;
  u16* dst = (w < 2) ? fK : fV;
  const int mh = w & 1;
  f32x4 acc[2][16];
#pragma unroll
  for (int mi = 0; mi < 2; ++mi)
#pragma unroll
    for (int nt = 0; nt < 16; ++nt) acc[mi][nt] = (f32x4){0.f,0.f,0.f,0.f};

  for (int kt = 0; kt < 8; ++kt) {
    bf16x8 a0 = ld_frag(&At[(mh << 5) + l15][(kt << 5) + (g << 3)]);
    bf16x8 a1 = ld_frag(&At[(mh << 5) + 16 + l15][(kt << 5) + (g << 3)]);
#pragma unroll
    for (int nt = 0; nt < 16; ++nt) {
      bf16x8 b = ld_frag_g(W + (size_t)((nt << 4) + l15)*256 + (kt << 5) + (g << 3));
      acc[0][nt] = MFMA(a0, b, acc[0][nt]);
      acc[1][nt] = MFMA(a1, b, acc[1][nt]);
    }
  }
#pragma unroll
  for (int mi = 0; mi < 2; ++mi)
#pragma unroll
    for (int nt = 0; nt < 16; ++nt)
#pragma unroll
      for (int i = 0; i < 4; ++i) {
        int m = (mh << 5) + (mi << 4) + (g << 2) + i;
        dst[(size_t)(m0 + m)*256 + (nt << 4) + l15] = f2bf(acc[mi][nt][i]);
      }
}

// ---------------- K2: qs[h][64][32] = (cq @ Wq_h^T + bq_h)/sqrt(32), rows 49..63 zero ----
__global__ void compute_qs(const float* __restrict__ cq, const float* __restrict__ ipw,
                           const float* __restrict__ ipb, u16* __restrict__ qs) {
  int h = blockIdx.x;
  int t = threadIdx.x;
  for (int r = 0; r < 8; ++r) {
    int o = t + 256*r;
    int qq = o >> 5, d = o & 31;
    float acc = 0.f;
    if (qq < NQ) {
      acc = ipb[h*32 + d];
      const float4* wr = (const float4*)(ipw + (size_t)(h*32 + d)*256);
      const float4* cr = (const float4*)(cq + (size_t)qq*256);
      float s = 0.f;
      for (int e = 0; e < 64; ++e) {
        float4 a = cr[e], b = wr[e];
        s += a.x*b.x + a.y*b.y + a.z*b.z + a.w*b.w;
      }
      acc = (acc + s) * 0.17677669529663687f;
    }
    qs[h*2048 + o] = f2bf(acc);
  }
}

// ---------------- K3: main fused kernel, one ROI per block, 2 blocks/CU ----------------
struct SMemA {
  u16 kh[208][KH_ST];     // 18,304 B  k_h [s][32d] (rows 196..207 garbage, masked)
  u16 vT[32][VT_ST];      // 14,592 B  v_h^T [d][s] (cols 196..223 zeroed once)
  u16 attn[64][AT_ST];    // 29,184 B  attn [q][s]  (cols 208..223 zeroed once)
  u16 ore[64][OR_ST];     //  5,632 B  per-head o redistribution
};
struct SMemC {
  u16 ast[64][AS_ST];     // 33,280 B  final att staging
  u16 pos[49][PS_ST];     // 25,480 B  pos staging
};
struct SMem {
  int   pbase[208];       // sampling params (shared by k/v/pos paths)
  int   pdx[208];
  int   pdy[208];
  float pw[208][4];
  union { SMemA a; SMemC c; } u;
};                        // total 73,536 B -> 2 blocks/CU

__global__ __launch_bounds__(256, 2) void fused_roi_attn(
    const float* __restrict__ rois,
    const float* __restrict__ balance_p,
    const float* __restrict__ bv,       // in_proj_bias + 512
    const float* __restrict__ bout,
    const u16*  __restrict__ fT,        // [HW][256] bf16
    const u16*  __restrict__ fK,        // [HW][256] bf16 (pre-projected K)
    const u16*  __restrict__ fV,        // [HW][256] bf16 (pre-projected V)
    const u16*  __restrict__ Woutbf,    // [256][256]
    const u16*  __restrict__ qsPad,     // [8][64][32]
    float* __restrict__ out)            // [512][256][49]
{
  __shared__ SMem sm;
  const int tid = threadIdx.x;
  const int lane = tid & 63;
  const int w = tid >> 6;
  const int g = lane >> 4;
  const int l15 = lane & 15;
  const int n = blockIdx.x;

  // ---- Phase A: sampling params (one grid point per thread) ----
  float x1 = rois[n*5 + 1], y1r = rois[n*5 + 2], x2 = rois[n*5 + 3], y2 = rois[n*5 + 4];
  const float sc = 1.0f/16.0f;
  float sx = x1*sc - 0.5f, sy = y1r*sc - 0.5f;
  float bw = (x2 - x1)*sc*(1.0f/14.0f);
  float bh = (y2 - y1r)*sc*(1.0f/14.0f);
  if (tid < S_TOT) {
    int s = tid;
    int gy = s/14, gx = s - gy*14;
    float y = sy + ((float)gy + 0.5f)*bh;
    float x = sx + ((float)gx + 0.5f)*bw;
    float valid = (y >= -1.0f && y <= (float)FH && x >= -1.0f && x <= (float)FW) ? 1.0f : 0.0f;
    float yc = fminf(fmaxf(y, 0.0f), (float)(FH-1));
    float xc = fminf(fmaxf(x, 0.0f), (float)(FW-1));
    float y0f = floorf(yc), x0f = floorf(xc);
    int y0 = (int)y0f, x0 = (int)x0f;
    int dy = (y0 + 1 < FH) ? FW : 0;
    int dx = (x0 + 1 < FW) ? 1 : 0;
    float ly = yc - y0f, lx = xc - x0f;
    float hy = 1.0f - ly, hx = 1.0f - lx;
    sm.pbase[s] = y0*FW + x0;
    sm.pdx[s] = dx; sm.pdy[s] = dy;
    sm.pw[s][0] = hy*hx*valid; sm.pw[s][1] = hy*lx*valid;
    sm.pw[s][2] = ly*hx*valid; sm.pw[s][3] = ly*lx*valid;
  }
  // zero pads once (NaN safety: attn==0 x garbage would still poison MFMA)
  for (int i = tid; i < 32*28; i += 256) { int r = i/28; sm.u.a.vT[r][196 + (i - r*28)] = 0; }
  for (int i = tid; i < 64*16; i += 256) sm.u.a.attn[i >> 4][208 + (i & 15)] = 0;

  float bal;
  { float bp = balance_p[0]; bal = fminf(fmaxf(bp*(1.0f/6.0f) + 0.5f, 0.0f), 1.0f); }

  f32x4 attacc[16];
#pragma unroll
  for (int i = 0; i < 16; ++i) attacc[i] = (f32x4){0.f,0.f,0.f,0.f};

  for (int h = 0; h < HEADS; ++h) {
    __syncthreads();   // params/pads ready (h=0); prior kh/vT reads done (h>0)

    // ---- sample k_h -> kh[s][32], v_h -> vT[d][s]; slot = (s, 16-ch half) ----
#pragma unroll
    for (int it = 0; it < 2; ++it) {
      int slot = tid + (it << 8);
      if (slot < 2*S_TOT) {
        int s = slot >> 1, hf = slot & 1;
        int b = sm.pbase[s];
        int o01 = sm.pdx[s] << 8;
        int o10 = sm.pdy[s] << 8;
        int o11 = o10 + o01;
        float w0 = sm.pw[s][0], w1 = sm.pw[s][1], w2 = sm.pw[s][2], w3 = sm.pw[s][3];
        const u16* pk = fK + ((size_t)b << 8) + (h << 5) + (hf << 4);
        const u16* pv = fV + ((size_t)b << 8) + (h << 5) + (hf << 4);
        us8 k00a = *(const us8*)(pk);       us8 k00b = *(const us8*)(pk + 8);
        us8 k01a = *(const us8*)(pk + o01); us8 k01b = *(const us8*)(pk + o01 + 8);
        us8 k10a = *(const us8*)(pk + o10); us8 k10b = *(const us8*)(pk + o10 + 8);
        us8 k11a = *(const us8*)(pk + o11); us8 k11b = *(const us8*)(pk + o11 + 8);
        us8 v00a = *(const us8*)(pv);       us8 v00b = *(const us8*)(pv + 8);
        us8 v01a = *(const us8*)(pv + o01); us8 v01b = *(const us8*)(pv + o01 + 8);
        us8 v10a = *(const us8*)(pv + o10); us8 v10b = *(const us8*)(pv + o10 + 8);
        us8 v11a = *(const us8*)(pv + o11); us8 v11b = *(const us8*)(pv + o11 + 8);
        float kk[16], vv[16];
#pragma unroll
        for (int c = 0; c < 8; ++c) {
          kk[c]   = w0*bf2f(k00a[c]) + w1*bf2f(k01a[c]) + w2*bf2f(k10a[c]) + w3*bf2f(k11a[c]);
          kk[c+8] = w0*bf2f(k00b[c]) + w1*bf2f(k01b[c]) + w2*bf2f(k10b[c]) + w3*bf2f(k11b[c]);
          vv[c]   = w0*bf2f(v00a[c]) + w1*bf2f(v01a[c]) + w2*bf2f(v10a[c]) + w3*bf2f(v11a[c]);
          vv[c+8] = w0*bf2f(v00b[c]) + w1*bf2f(v01b[c]) + w2*bf2f(v10b[c]) + w3*bf2f(v11b[c]);
        }
        u16* krow = &sm.u.a.kh[s][hf << 4];
        *(ushort4*)(krow)      = pack4(kk[0],  kk[1],  kk[2],  kk[3]);
        *(ushort4*)(krow + 4)  = pack4(kk[4],  kk[5],  kk[6],  kk[7]);
        *(ushort4*)(krow + 8)  = pack4(kk[8],  kk[9],  kk[10], kk[11]);
        *(ushort4*)(krow + 12) = pack4(kk[12], kk[13], kk[14], kk[15]);
#pragma unroll
        for (int j = 0; j < 16; ++j) sm.u.a.vT[(hf << 4) + j][s] = f2bf(vv[j]);
      }
    }
    __syncthreads();   // kh, vT ready

    // ---- logits[q=16w+4g+i][s=16nt+l15] ----
    bf16x8 aq = ld_frag_g(qsPad + (size_t)((h << 6) + (w << 4) + l15)*32 + (g << 3));
    f32x4 lac[13];
#pragma unroll
    for (int nt = 0; nt < 13; ++nt) {
      bf16x8 bk = ld_frag(&sm.u.a.kh[(nt << 4) + l15][g << 3]);
      f32x4 z = (f32x4){0.f,0.f,0.f,0.f};
      lac[nt] = MFMA(aq, bk, z);
    }
    if (l15 >= 4) {      // mask s >= 196 (kh pad rows are garbage -> overwrite)
#pragma unroll
      for (int i = 0; i < 4; ++i) lac[12][i] = -1e30f;
    }
    // ---- softmax over s ----
    float srow[4];
#pragma unroll
    for (int i = 0; i < 4; ++i) {
      float m = lac[0][i];
#pragma unroll
      for (int nt = 1; nt < 13; ++nt) m = fmaxf(m, lac[nt][i]);
#pragma unroll
      for (int off = 1; off < 16; off <<= 1) m = fmaxf(m, __shfl_xor(m, off, 64));
      float sumv = 0.f;
#pragma unroll
      for (int nt = 0; nt < 13; ++nt) {
        float p = __expf(lac[nt][i] - m);
        lac[nt][i] = p; sumv += p;
      }
#pragma unroll
      for (int off = 1; off < 16; off <<= 1) sumv += __shfl_xor(sumv, off, 64);
      srow[i] = 1.0f / sumv;
    }
    // attn rows are wave-local (written+read by wave w only) -> no barrier
#pragma unroll
    for (int nt = 0; nt < 13; ++nt)
#pragma unroll
      for (int i = 0; i < 4; ++i)
        sm.u.a.attn[(w << 4) + (g << 2) + i][(nt << 4) + l15] = f2bf(lac[nt][i]*srow[i]);

    // ---- PV: o_h = attn @ v ----
    f32x4 o0 = (f32x4){0.f,0.f,0.f,0.f}, o1 = (f32x4){0.f,0.f,0.f,0.f};
#pragma unroll
    for (int kt = 0; kt < 7; ++kt) {
      bf16x8 ap = ld_frag(&sm.u.a.attn[(w << 4) + l15][(kt << 5) + (g << 3)]);
      bf16x8 b0 = ld_frag(&sm.u.a.vT[l15][(kt << 5) + (g << 3)]);
      bf16x8 b1 = ld_frag(&sm.u.a.vT[16 + l15][(kt << 5) + (g << 3)]);
      o0 = MFMA(ap, b0, o0);
      o1 = MFMA(ap, b1, o1);
    }
    // bias (bv commutes through softmax) + redistribute to A-frag layout (wave-local)
    float bv0 = bv[(h << 5) + l15];
    float bv1 = bv[(h << 5) + 16 + l15];
#pragma unroll
    for (int i = 0; i < 4; ++i) {
      sm.u.a.ore[(w << 4) + (g << 2) + i][l15]      = f2bf(o0[i] + bv0);
      sm.u.a.ore[(w << 4) + (g << 2) + i][16 + l15] = f2bf(o1[i] + bv1);
    }
    // ---- out-projection K-split accumulate ----
    bf16x8 ao = ld_frag(&sm.u.a.ore[(w << 4) + l15][g << 3]);
#pragma unroll
    for (int nt = 0; nt < 16; ++nt) {
      bf16x8 bo = ld_frag_g(Woutbf + (size_t)((nt << 4) + l15)*256 + (h << 5) + (g << 3));
      attacc[nt] = MFMA(ao, bo, attacc[nt]);
    }
  } // heads

  // ---- Phase C: stage att, sample pos directly from fT, blend, coalesced store ----
  __syncthreads();   // all kh/vT/attn/ore reads done before aliasing ast/pos
#pragma unroll
  for (int nt = 0; nt < 16; ++nt) {
    float bo = bout[(nt << 4) + l15];
#pragma unroll
    for (int i = 0; i < 4; ++i)
      sm.u.c.ast[(w << 4) + (g << 2) + i][(nt << 4) + l15] = f2bf(attacc[nt][i] + bo);
  }
  // pos[q][c]: 4-point avg of bilinear samples at the 14x14 grid (exact identity)
  for (int it = 0; it < 13; ++it) {
    int item = tid + (it << 8);
    if (item < NQ*64) {
      int q = item >> 6, cg = item & 63;
      int oy = q/7, ox = q - oy*7;
      float a0 = 0.f, a1 = 0.f, a2 = 0.f, a3 = 0.f;
#pragma unroll
      for (int jj = 0; jj < 2; ++jj)
#pragma unroll
        for (int ii = 0; ii < 2; ++ii) {
          int s = ((oy << 1) + jj)*14 + (ox << 1) + ii;
          int b = sm.pbase[s];
          int o01 = sm.pdx[s] << 8;
          int o10 = sm.pdy[s] << 8;
          float w0 = sm.pw[s][0], w1 = sm.pw[s][1], w2 = sm.pw[s][2], w3 = sm.pw[s][3];
          const u16* pt = fT + ((size_t)b << 8) + (cg << 2);
          ushort4 c00 = *(const ushort4*)(pt);
          ushort4 c01 = *(const ushort4*)(pt + o01);
          ushort4 c10 = *(const ushort4*)(pt + o10);
          ushort4 c11 = *(const ushort4*)(pt + o10 + o01);
          a0 += w0*bf2f(c00.x) + w1*bf2f(c01.x) + w2*bf2f(c10.x) + w3*bf2f(c11.x);
          a1 += w0*bf2f(c00.y) + w1*bf2f(c01.y) + w2*bf2f(c10.y) + w3*bf2f(c11.y);
          a2 += w0*bf2f(c00.z) + w1*bf2f(c01.z) + w2*bf2f(c10.z) + w3*bf2f(c11.z);
          a3 += w0*bf2f(c00.w) + w1*bf2f(c01.w) + w2*bf2f(c10.w) + w3*bf2f(c11.w);
        }
      *(ushort4*)(&sm.u.c.pos[q][cg << 2]) = pack4(0.25f*a0, 0.25f*a1, 0.25f*a2, 0.25f*a3);
    }
  }
  __syncthreads();
  float ibal = 1.0f - bal;
  float* outp = out + (size_t)n*(E_DIM*NQ);
  for (int j = 0; j < 49; ++j) {
    int idx = (j << 8) + tid;        // 12544 = 49*256 exactly
    int eo = idx/49;
    int q  = idx - eo*49;
    outp[idx] = bal*bf2f(sm.u.c.pos[q][eo]) + ibal*bf2f(sm.u.c.ast[q][eo]);
  }
}

// ---------------- launcher ----------------
// ws: fT | fK | fV (19,922,944 B each) | Wk | Wv | Wo (131,072 each) | qs 32,768
extern "C" void kernel_launch(void* const* d_in, const int* in_sizes, int n_in,
                              void* d_out, int out_size, void* d_ws, size_t ws_size,
                              hipStream_t stream) {
  const float* features = (const float*)d_in[0];
  const float* rois     = (const float*)d_in[1];
  const float* cq       = (const float*)d_in[2];
  const float* ipw      = (const float*)d_in[3];
  const float* ipb      = (const float*)d_in[4];
  const float* opw      = (const float*)d_in[5];
  const float* opb      = (const float*)d_in[6];
  const float* balp     = (const float*)d_in[7];
  float* out = (float*)d_out;

  char* ws = (char*)d_ws;
  const size_t FMB = (size_t)HW_TOT*256*2;   // 19,922,944
  u16* fT = (u16*)ws;
  u16* fK = (u16*)(ws + FMB);
  u16* fV = (u16*)(ws + 2*FMB);
  u16* Wk = (u16*)(ws + 3*FMB);
  u16* Wv = Wk + 65536;
  u16* Wo = Wv + 65536;
  u16* qs = Wo + 65536;

  hipLaunchKernelGGL(conv_weights,   dim3(256), dim3(256), 0, stream, ipw, opw, Wk, Wv, Wo);
  hipLaunchKernelGGL(prep_fmaps,     dim3(HW_TOT/64), dim3(256), 0, stream,
                     features, Wk, Wv, fT, fK, fV);
  hipLaunchKernelGGL(compute_qs,     dim3(8),   dim3(256), 0, stream, cq, ipw, ipb, qs);
  hipLaunchKernelGGL(fused_roi_attn, dim3(NROIS), dim3(256), 0, stream,
                     rois, balp, ipb + 512, opb, fT, fK, fV, Wo, qs, out);
}